// Round 1
// baseline (84023.126 us; speedup 1.0000x reference)
//
#include <hip/hip_runtime.h>
#include <hip/hip_bf16.h>
#include <math.h>

// Problem constants (fixed by the reference)
#define T_STEPS 4096
#define N_IN    8192
#define N_OUT   2048
#define ALPHA_F 0.5f

// ---------------------------------------------------------------------------
// Kernel 1: u_proj = x @ Win   (f32 vector GEMM, 128x128 tile, BK=16)
//   x:   [4096, 8192] row-major
//   Win: [8192, 2048] row-major
//   U:   [4096, 2048] row-major  (written into d_out; recurrence consumes it)
// ---------------------------------------------------------------------------
#define GM_BK 16

__global__ __launch_bounds__(256) void gemm_xwin(const float* __restrict__ X,
                                                 const float* __restrict__ Win,
                                                 float* __restrict__ U) {
    const int K = N_IN, N = N_OUT;
    // A tile stored TRANSPOSED (As[k][m]) so compute reads are contiguous b128.
    __shared__ float As[GM_BK][128 + 4];   // stride 132 words: b128-aligned, 2-way banks max
    __shared__ float Bs[GM_BK][128 + 4];

    const int tid = threadIdx.x;
    const int bm = blockIdx.x;   // 32 tiles of M
    const int bn = blockIdx.y;   // 16 tiles of N
    const int tx = tid & 15;
    const int ty = tid >> 4;

    float acc[8][8];
#pragma unroll
    for (int i = 0; i < 8; i++)
#pragma unroll
        for (int j = 0; j < 8; j++) acc[i][j] = 0.f;

    const float* Xb = X + (size_t)(bm * 128) * K;
    const float* Wb = Win + bn * 128;

    for (int kt = 0; kt < K; kt += GM_BK) {
        // ---- stage A (128 rows x 16 k), transposed into As[k][m] ----
#pragma unroll
        for (int q = 0; q < 2; q++) {
            const int r  = (tid >> 2) + q * 64;       // 0..127
            const int c4 = (tid & 3) * 4;             // 0,4,8,12
            const float4 a4 = *reinterpret_cast<const float4*>(&Xb[(size_t)r * K + kt + c4]);
            As[c4 + 0][r] = a4.x;
            As[c4 + 1][r] = a4.y;
            As[c4 + 2][r] = a4.z;
            As[c4 + 3][r] = a4.w;
        }
        // ---- stage B (16 k x 128 cols) ----
#pragma unroll
        for (int q = 0; q < 2; q++) {
            const int r  = (tid >> 5) + q * 8;        // 0..15
            const int c4 = (tid & 31) * 4;            // 0..124
            *reinterpret_cast<float4*>(&Bs[r][c4]) =
                *reinterpret_cast<const float4*>(&Wb[(size_t)(kt + r) * N + c4]);
        }
        __syncthreads();

#pragma unroll
        for (int k = 0; k < GM_BK; k++) {
            float a[8], b[8];
#pragma unroll
            for (int i = 0; i < 4; i++) {
                a[i]     = As[k][ty * 4 + i];
                a[4 + i] = As[k][64 + ty * 4 + i];
            }
#pragma unroll
            for (int j = 0; j < 4; j++) {
                b[j]     = Bs[k][tx * 4 + j];
                b[4 + j] = Bs[k][64 + tx * 4 + j];
            }
#pragma unroll
            for (int i = 0; i < 8; i++)
#pragma unroll
                for (int j = 0; j < 8; j++)
                    acc[i][j] = fmaf(a[i], b[j], acc[i][j]);
        }
        __syncthreads();
    }

    // ---- write C; rows/cols split as {4ty..4ty+3, 64+4ty..} x {4tx.., 64+4tx..} ----
#pragma unroll
    for (int i = 0; i < 8; i++) {
        const int mr = bm * 128 + ((i < 4) ? (ty * 4 + i) : (64 + ty * 4 + (i - 4)));
        float* Crow = U + (size_t)mr * N + bn * 128;
        float4 v0 = make_float4(acc[i][0], acc[i][1], acc[i][2], acc[i][3]);
        float4 v1 = make_float4(acc[i][4], acc[i][5], acc[i][6], acc[i][7]);
        *reinterpret_cast<float4*>(&Crow[tx * 4])      = v0;
        *reinterpret_cast<float4*>(&Crow[64 + tx * 4]) = v1;
    }
}

// ---------------------------------------------------------------------------
// Kernel 2: the sequential ESN recurrence.
//   128 co-resident blocks (<= 256 CUs, guaranteed resident), 256 threads.
//   Block b owns 16 output columns; W's ~10%-dense columns are compacted into
//   LDS once (values + row indices), then each of the 4096 steps only needs
//   the 8 KB state vector, exchanged through a double buffer + flag barrier
//   with agent-scope atomics (cross-XCD coherent).
//   UO: read u_proj[t][j], then overwrite with v[t][j] in-place.
// ---------------------------------------------------------------------------
#define RB   128   // blocks
#define CPB  16    // columns per block
#define CAP  352   // nnz capacity per column (mean 204.8, sigma 13.6 -> 10.8 sigma)

__global__ __launch_bounds__(256) void esn_recur(const float* __restrict__ W,
                                                 float* __restrict__ UO,
                                                 float* vbuf,   // ws: 2 x N_OUT floats
                                                 int* flags) {  // ws: RB ints
    __shared__ float vals[CPB][CAP];
    __shared__ int   idxs[CPB][CAP];
    __shared__ int   cnts[CPB];
    __shared__ float vsh[N_OUT];

    const int tid = threadIdx.x;
    const int b   = blockIdx.x;
    const int c   = tid >> 4;              // column group 0..15
    const int l   = tid & 15;              // lane within group
    const int j   = b * CPB + c;           // global output column

    // ---------- build sparse column (one-time; two passes over W[:, j]) ----------
    int cnt = 0;
    for (int k = 0; k < N_OUT / 16; k++) {
        const int i = l + 16 * k;
        const float w = W[(size_t)i * N_OUT + j];
        cnt += (w != 0.0f) ? 1 : 0;
    }
    // inclusive scan over the 16-lane group (groups are 16-aligned within a wave)
    int inc = cnt;
#pragma unroll
    for (int d = 1; d < 16; d <<= 1) {
        int n = __shfl_up(inc, d, 64);
        if (l >= d) inc += n;
    }
    const int excl = inc - cnt;
    if (l == 15) cnts[c] = inc;
    int pos = excl;
    for (int k = 0; k < N_OUT / 16; k++) {
        const int i = l + 16 * k;
        const float w = W[(size_t)i * N_OUT + j];
        if (w != 0.0f) {
            if (pos < CAP) { vals[c][pos] = w; idxs[c][pos] = i; }
            pos++;
        }
    }
    __syncthreads();
    int ccnt = cnts[c];
    if (ccnt > CAP) ccnt = CAP;

    // ---------- sequential scan over T ----------
#pragma unroll 1
    for (int t = 0; t < T_STEPS; t++) {
        if (t > 0) {
            if (tid < RB) {
                while (__hip_atomic_load(&flags[tid], __ATOMIC_RELAXED,
                                         __HIP_MEMORY_SCOPE_AGENT) < t) { /* spin */ }
            }
            __syncthreads();
            __threadfence();   // acquire: make other blocks' v stores visible
        }

        const float* vin = vbuf + (size_t)(t & 1) * N_OUT;
        // stage v_t into LDS (agent-scope loads bypass stale L1/L2)
#pragma unroll
        for (int q = 0; q < N_OUT / 256; q++) {
            const int i = tid + q * 256;
            vsh[i] = __hip_atomic_load(&vin[i], __ATOMIC_RELAXED, __HIP_MEMORY_SCOPE_AGENT);
        }
        // leader also issues its u load; both drain at the barrier's vmcnt(0)
        float u = 0.f;
        if (l == 0) u = UO[(size_t)t * N_OUT + j];
        __syncthreads();

        // sparse MAC: y[j] = sum_i v[i] * W[i][j]
        float y = 0.f;
        for (int p = l; p < ccnt; p += 16) {
            y = fmaf(vals[c][p], vsh[idxs[c][p]], y);
        }
#pragma unroll
        for (int d = 8; d >= 1; d >>= 1) y += __shfl_xor(y, d, 64);

        if (l == 0) {
            const float vold = vsh[j];
            const float vnew = (1.0f - ALPHA_F) * vold + ALPHA_F * tanhf(y + u);
            UO[(size_t)t * N_OUT + j] = vnew;  // overwrite u with the output state
            __hip_atomic_store(&vbuf[(size_t)((t + 1) & 1) * N_OUT + j], vnew,
                               __ATOMIC_RELEASE, __HIP_MEMORY_SCOPE_AGENT);
        }
        __syncthreads();   // drains vmcnt(0): all leaders' stores are at the coherent point
        if (tid == 0) {
            __hip_atomic_store(&flags[b], t + 1, __ATOMIC_RELEASE, __HIP_MEMORY_SCOPE_AGENT);
        }
    }
}

// ---------------------------------------------------------------------------
extern "C" void kernel_launch(void* const* d_in, const int* in_sizes, int n_in,
                              void* d_out, int out_size, void* d_ws, size_t ws_size,
                              hipStream_t stream) {
    const float* x   = (const float*)d_in[0];   // [4096, 8192]
    const float* W   = (const float*)d_in[1];   // [2048, 2048]
    const float* Win = (const float*)d_in[2];   // [8192, 2048]
    float* out = (float*)d_out;                 // [4096, 2048]

    float* vbuf  = (float*)d_ws;                              // 2 x 2048 f32
    int*   flags = (int*)((char*)d_ws + 2 * N_OUT * sizeof(float));  // RB ints

    // zero v0 state + flags (graph-capturable)
    hipMemsetAsync(d_ws, 0, 2 * N_OUT * sizeof(float) + RB * sizeof(int), stream);

    // u_proj -> d_out (same shape); recurrence reads u then overwrites in-place
    dim3 ggrid(T_STEPS / 128, N_OUT / 128);
    gemm_xwin<<<ggrid, 256, 0, stream>>>(x, Win, out);

    esn_recur<<<RB, 256, 0, stream>>>(W, out, vbuf, flags);
}

// Round 2
// 17067.207 us; speedup vs baseline: 4.9231x; 4.9231x over previous
//
#include <hip/hip_runtime.h>
#include <hip/hip_bf16.h>
#include <math.h>

// Problem constants (fixed by the reference)
#define T_STEPS 4096
#define N_IN    8192
#define N_OUT   2048

// ---------------------------------------------------------------------------
// Kernel 1: u_proj = x @ Win   (f32 vector GEMM, 128x128 tile, BK=16)
//   Writes into d_out; the recurrence consumes/overwrites it in place.
// ---------------------------------------------------------------------------
#define GM_BK 16

__global__ __launch_bounds__(256) void gemm_xwin(const float* __restrict__ X,
                                                 const float* __restrict__ Win,
                                                 float* __restrict__ U) {
    const int K = N_IN, N = N_OUT;
    __shared__ float As[GM_BK][128 + 4];
    __shared__ float Bs[GM_BK][128 + 4];

    const int tid = threadIdx.x;
    const int bm = blockIdx.x;
    const int bn = blockIdx.y;
    const int tx = tid & 15;
    const int ty = tid >> 4;

    float acc[8][8];
#pragma unroll
    for (int i = 0; i < 8; i++)
#pragma unroll
        for (int j = 0; j < 8; j++) acc[i][j] = 0.f;

    const float* Xb = X + (size_t)(bm * 128) * K;
    const float* Wb = Win + bn * 128;

    for (int kt = 0; kt < K; kt += GM_BK) {
#pragma unroll
        for (int q = 0; q < 2; q++) {
            const int r  = (tid >> 2) + q * 64;
            const int c4 = (tid & 3) * 4;
            const float4 a4 = *reinterpret_cast<const float4*>(&Xb[(size_t)r * K + kt + c4]);
            As[c4 + 0][r] = a4.x;
            As[c4 + 1][r] = a4.y;
            As[c4 + 2][r] = a4.z;
            As[c4 + 3][r] = a4.w;
        }
#pragma unroll
        for (int q = 0; q < 2; q++) {
            const int r  = (tid >> 5) + q * 8;
            const int c4 = (tid & 31) * 4;
            *reinterpret_cast<float4*>(&Bs[r][c4]) =
                *reinterpret_cast<const float4*>(&Wb[(size_t)(kt + r) * N + c4]);
        }
        __syncthreads();

#pragma unroll
        for (int k = 0; k < GM_BK; k++) {
            float a[8], b[8];
#pragma unroll
            for (int i = 0; i < 4; i++) {
                a[i]     = As[k][ty * 4 + i];
                a[4 + i] = As[k][64 + ty * 4 + i];
            }
#pragma unroll
            for (int j = 0; j < 4; j++) {
                b[j]     = Bs[k][tx * 4 + j];
                b[4 + j] = Bs[k][64 + tx * 4 + j];
            }
#pragma unroll
            for (int i = 0; i < 8; i++)
#pragma unroll
                for (int j = 0; j < 8; j++)
                    acc[i][j] = fmaf(a[i], b[j], acc[i][j]);
        }
        __syncthreads();
    }

#pragma unroll
    for (int i = 0; i < 8; i++) {
        const int mr = bm * 128 + ((i < 4) ? (ty * 4 + i) : (64 + ty * 4 + (i - 4)));
        float* Crow = U + (size_t)mr * N + bn * 128;
        float4 v0 = make_float4(acc[i][0], acc[i][1], acc[i][2], acc[i][3]);
        float4 v1 = make_float4(acc[i][4], acc[i][5], acc[i][6], acc[i][7]);
        *reinterpret_cast<float4*>(&Crow[tx * 4])      = v0;
        *reinterpret_cast<float4*>(&Crow[64 + tx * 4]) = v1;
    }
}

// ---------------------------------------------------------------------------
// Kernel 2: sequential ESN recurrence with TAGGED-SLOT data exchange.
//   256 co-resident blocks (1/CU), 8 columns each, 32 lanes per column.
//   Each state element lives in a 64-bit slot {tag=t (hi32), f32 bits (lo32)},
//   double-buffered by step parity. Readers poll the slot until tag==t:
//   the data IS the barrier — no flags, no fences, one LLC round-trip.
//   Buffer-reuse safety: writing v_{t+1} over v_{t-1} requires having read all
//   of v_t, which implies every block finished reading v_{t-1}.
// ---------------------------------------------------------------------------
#define RB   256   // blocks (== CU count, co-resident by construction)
#define CPB  8     // columns per block
#define GRP  32    // lanes per column
#define CAP  352   // nnz capacity per column (mean 204.8, sigma 13.6)

__global__ __launch_bounds__(256) void esn_recur(const float* __restrict__ W,
                                                 float* __restrict__ UO,
                                                 unsigned long long* vslots) {
    __shared__ unsigned long long ent[CPB][CAP];  // {idx (hi32), w bits (lo32)}
    __shared__ int   cnts[CPB];
    __shared__ float vsh[N_OUT];

    const int tid = threadIdx.x;
    const int b   = blockIdx.x;
    const int c   = tid >> 5;              // column group 0..7
    const int l   = tid & 31;              // lane within group
    const int j   = b * CPB + c;           // global output column

    // ---------- build sparse column (one-time) ----------
    int cnt = 0;
    for (int k = 0; k < N_OUT / GRP; k++) {
        const float w = W[(size_t)(l + GRP * k) * N_OUT + j];
        cnt += (w != 0.0f) ? 1 : 0;
    }
    int inc = cnt;
#pragma unroll
    for (int d = 1; d < GRP; d <<= 1) {
        int n = __shfl_up(inc, d, 64);
        if (l >= d) inc += n;
    }
    int pos = inc - cnt;
    if (l == GRP - 1) cnts[c] = inc;
    for (int k = 0; k < N_OUT / GRP; k++) {
        const int i = l + GRP * k;
        const float w = W[(size_t)i * N_OUT + j];
        if (w != 0.0f) {
            if (pos < CAP)
                ent[c][pos] = ((unsigned long long)(unsigned)i << 32) | __float_as_uint(w);
            pos++;
        }
    }
    __syncthreads();
    const int ccnt = min(cnts[c], CAP);

    // ---------- sequential scan over T ----------
#pragma unroll 1
    for (int t = 0; t < T_STEPS; t++) {
        // prefetch this step's input projection (independent of v_t)
        float u = 0.f;
        if (l == 0) u = UO[(size_t)t * N_OUT + j];

        // poll tagged slots for v_t (8 independent slots per thread)
        unsigned long long* vin = vslots + (size_t)(t & 1) * N_OUT;
        unsigned long long uq[8];
#pragma unroll
        for (int q = 0; q < 8; q++)
            uq[q] = __hip_atomic_load(&vin[tid + q * 256], __ATOMIC_RELAXED,
                                      __HIP_MEMORY_SCOPE_AGENT);
#pragma unroll
        for (int q = 0; q < 8; q++) {
            while ((unsigned)(uq[q] >> 32) != (unsigned)t)
                uq[q] = __hip_atomic_load(&vin[tid + q * 256], __ATOMIC_RELAXED,
                                          __HIP_MEMORY_SCOPE_AGENT);
            vsh[tid + q * 256] = __uint_as_float((unsigned)uq[q]);
        }
        __syncthreads();

        // sparse MAC: y[j] = sum_i W[i][j] * v_t[i]
        float y = 0.f;
        for (int p = l; p < ccnt; p += GRP) {
            const unsigned long long e = ent[c][p];
            y = fmaf(__uint_as_float((unsigned)e), vsh[e >> 32], y);
        }
#pragma unroll
        for (int d = 16; d >= 1; d >>= 1) y += __shfl_xor(y, d, 64);

        if (l == 0) {
            const float vnew = 0.5f * vsh[j] + 0.5f * tanhf(y + u);
            UO[(size_t)t * N_OUT + j] = vnew;   // overwrite u with output state
            const unsigned long long slot =
                ((unsigned long long)(unsigned)(t + 1) << 32) | __float_as_uint(vnew);
            __hip_atomic_store(&vslots[(size_t)((t + 1) & 1) * N_OUT + j], slot,
                               __ATOMIC_RELAXED, __HIP_MEMORY_SCOPE_AGENT);
        }
        __syncthreads();   // vsh stable until all waves leave the MAC phase
    }
}

// ---------------------------------------------------------------------------
extern "C" void kernel_launch(void* const* d_in, const int* in_sizes, int n_in,
                              void* d_out, int out_size, void* d_ws, size_t ws_size,
                              hipStream_t stream) {
    const float* x   = (const float*)d_in[0];   // [4096, 8192]
    const float* W   = (const float*)d_in[1];   // [2048, 2048]
    const float* Win = (const float*)d_in[2];   // [8192, 2048]
    float* out = (float*)d_out;                 // [4096, 2048]

    unsigned long long* vslots = (unsigned long long*)d_ws;  // 2 x N_OUT x 8B

    // zero tags+values: slot[0] becomes {tag=0, v=0} == the ESN zero state
    hipMemsetAsync(d_ws, 0, 2 * N_OUT * sizeof(unsigned long long), stream);

    dim3 ggrid(T_STEPS / 128, N_OUT / 128);
    gemm_xwin<<<ggrid, 256, 0, stream>>>(x, Win, out);

    esn_recur<<<RB, 256, 0, stream>>>(W, out, vslots);
}